// Round 18
// baseline (149.879 us; speedup 1.0000x reference)
//
#include <hip/hip_runtime.h>

#define MM      32768
#define OUTN    65536
#define NBC     64                 // output blocks of 1024 bins
#define TPB     256
#define NSTW    32                 // i0-steps per unit
#define MAXU    34                 // max units per block (real max 33)
#define APL     2048               // A plane bytes in LDS (504 dw live)
#define AREG    (3 * APL)          // 6144
#define BPL     1096               // B (q,r) plane bytes in LDS (272 dw live)
#define LDSZ    (AREG + 12 * BPL)  // 19296; red[16KB] aliases lds[0..)
#define GASZ    9216               // gRA plane dwords
#define GBSZ    9216               // gB plane dwords
#define GG      2048               // gB leading guard bytes
#define AMAXTOP 34816              // global reversed-A origin limb (mult of 32)
#define GA_B    0
#define GB_B    (3 * GASZ * 4)     // 110592
#define PART_B  (GB_B + 12 * GBSZ * 4)       // 552960
#define CTR_B   (PART_B + NBC * MAXU * 4096) // per-blk completion counters

typedef int i32x4  __attribute__((ext_vector_type(4)));
typedef int i32x16 __attribute__((ext_vector_type(16)));

__host__ __device__ inline void blk_params(int b, int nstw, int* Istart, int* units) {
    const int c0 = b << 10;
    int iLo = c0 - (MM - 1); if (iLo < 0) iLo = 0;
    int iHi = c0 + 1023;     if (iHi > MM - 1) iHi = MM - 1;
    const int Is = (iLo - 961) & ~31;
    const int Ie = (iHi + 31) & ~31;
    const int steps = ((Ie - Is) >> 5) + 1;
    *Istart = Is;
    *units  = (steps + nstw - 1) / nstw;
}

__device__ __forceinline__ int swzA(int a) {
    return a ^ ((a >> 2) & 0x30) ^ ((a >> 4) & 0x30);
}
__device__ __forceinline__ unsigned ldv(const int* __restrict__ p, int x) {
    return ((unsigned)x < (unsigned)MM) ? (unsigned)p[x] : 0u;
}
__device__ __forceinline__ unsigned pk4(unsigned b0, unsigned b1, unsigned b2, unsigned b3) {
    return b0 | (b1 << 8) | (b2 << 16) | (b3 << 24);
}
__device__ __forceinline__ i32x16 z16() {
    i32x16 v;
#pragma unroll
    for (int i = 0; i < 16; ++i) v[i] = 0;
    return v;
}

// grid (36, 5): y==0 -> reversed-A digit planes (+ ctr zeroing); y==r+1 -> B
// phase-r planes.  gRA_p byte u <-> digit_p(A[AMAXTOP-u]);
// gB (q,r) byte g <-> digit_q(B[g - GG + r])   [verified R16]
__global__ __launch_bounds__(TPB) void pack_kernel(
    const int* __restrict__ A, const int* __restrict__ B, char* __restrict__ w8)
{
    const int g4 = (int)blockIdx.x * TPB + (int)threadIdx.x;   // dword index < 9216
    if (blockIdx.y == 0) {
        if (blockIdx.x == 0 && threadIdx.x < NBC) {
            ((unsigned*)(w8 + CTR_B))[threadIdx.x] = 0u;       // completion ctrs
        }
        unsigned* gRA = (unsigned*)(w8 + GA_B);
        const int x0 = AMAXTOP - 4 * g4;
        const unsigned v0 = ldv(A, x0),     v1 = ldv(A, x0 - 1);
        const unsigned v2 = ldv(A, x0 - 2), v3 = ldv(A, x0 - 3);
        gRA[0 * GASZ + g4] = pk4(v0 & 127, v1 & 127, v2 & 127, v3 & 127);
        gRA[1 * GASZ + g4] = pk4((v0 >> 7) & 127, (v1 >> 7) & 127,
                                 (v2 >> 7) & 127, (v3 >> 7) & 127);
        gRA[2 * GASZ + g4] = pk4(v0 >> 14, v1 >> 14, v2 >> 14, v3 >> 14);
    } else {
        const int r = (int)blockIdx.y - 1;                     // byte phase 0..3
        unsigned* gB = (unsigned*)(w8 + GB_B);
        const int L = 4 * g4 - GG + r;
        const unsigned u0 = ldv(B, L),     u1 = ldv(B, L + 1);
        const unsigned u2 = ldv(B, L + 2), u3 = ldv(B, L + 3);
        gB[(0 * 4 + r) * GBSZ + g4] = pk4(u0 & 127, u1 & 127, u2 & 127, u3 & 127);
        gB[(1 * 4 + r) * GBSZ + g4] = pk4((u0 >> 7) & 127, (u1 >> 7) & 127,
                                          (u2 >> 7) & 127, (u3 >> 7) & 127);
        gB[(2 * 4 + r) * GBSZ + g4] = pk4(u0 >> 14, u1 >> 14, u2 >> 14, u3 >> 14);
    }
}

// One workgroup = one unit: 1024 bins, 32 i0-steps (4 waves x 8 steps).
// Hot loop byte-identical to the verified R16 kernel. New: the LAST finishing
// workgroup of each blk sums all its slices and writes out[] (threadfence
// reduction) -- removes the separate reduce launch.
__global__ __launch_bounds__(TPB, 4) void conv_mfma(
    const char* __restrict__ gA, const char* __restrict__ gB,
    unsigned* __restrict__ part, unsigned* __restrict__ ctr,
    unsigned* __restrict__ out)
{
    __shared__ __align__(16) char lds[LDSZ];
    __shared__ unsigned qSh;

    const int blk = (int)blockIdx.y;
    const int id  = (int)blockIdx.x;
    int Istart, un;
    blk_params(blk, NSTW, &Istart, &un);
    if (id >= un) return;

    const int c0  = blk << 10;
    const int S0  = Istart + 1024 * id;
    const int OFA = (AMAXTOP - S0 - 1984) >> 2;   // gRA dword base
    const int OFB = (c0 - S0 + 1056) >> 2;        // gB dword base
    const int l   = (int)threadIdx.x;
    const unsigned* gA4 = (const unsigned*)gA;
    const unsigned* gB4 = (const unsigned*)gB;

    // ---- Stage A: 504 dwords x 3 planes, swizzled dest (pure copy) ----
#pragma unroll
    for (int it = 0; it < 2; ++it) {
        const int w = l + (it << 8);
        if (w < 504) {
            const int wa = swzA(4 * w);
            *(unsigned*)&lds[0 * APL + wa] = gA4[0 * GASZ + OFA + w];
            *(unsigned*)&lds[1 * APL + wa] = gA4[1 * GASZ + OFA + w];
            *(unsigned*)&lds[2 * APL + wa] = gA4[2 * GASZ + OFA + w];
        }
    }
    // ---- Stage B: 272 dwords x 12 (q,r) planes (pure copy) ----
#pragma unroll
    for (int pl = 0; pl < 12; ++pl) {
        *(unsigned*)&lds[AREG + pl * BPL + 4 * l] = gB4[pl * GBSZ + OFB + l];
    }
    if (l < 16) {
#pragma unroll
        for (int pl = 0; pl < 12; ++pl) {
            *(unsigned*)&lds[AREG + pl * BPL + 4 * (l + 256)] =
                gB4[pl * GBSZ + OFB + l + 256];
        }
    }
    __syncthreads();

    const int wv = l >> 6;
    const int ll = l & 63;
    const int n  = ll & 31, h = ll >> 5;
    const int A0 = 1984 + 16 * h - 32 * n;
    const int B0 = AREG + (n & 3) * BPL + 4 * (248 + 4 * h + (n >> 2));

    i32x16 acc0 = z16(), acc1 = z16(), acc2 = z16(), acc3 = z16(), acc4 = z16();

#pragma unroll
    for (int j = 0; j < 8; ++j) {
        const int s = wv + 4 * j;                 // this wave's 8 of 32 steps
        const int aa = swzA(A0 - 32 * s);
        const i32x4 a0 = *(const i32x4*)&lds[aa];
        const i32x4 a1 = *(const i32x4*)&lds[APL + aa];
        const i32x4 a2 = *(const i32x4*)&lds[2 * APL + aa];
        const int bb = B0 - 32 * s;
        i32x4 b0, b1, b2;
#pragma unroll
        for (int q = 0; q < 4; ++q) {
            b0[q] = *(const int*)&lds[bb + 4 * q];
            b1[q] = *(const int*)&lds[bb + 4 * BPL + 4 * q];
            b2[q] = *(const int*)&lds[bb + 8 * BPL + 4 * q];
        }
        acc0 = __builtin_amdgcn_mfma_i32_32x32x32_i8(a0, b0, acc0, 0, 0, 0);
        acc1 = __builtin_amdgcn_mfma_i32_32x32x32_i8(a0, b1, acc1, 0, 0, 0);
        acc2 = __builtin_amdgcn_mfma_i32_32x32x32_i8(a0, b2, acc2, 0, 0, 0);
        acc3 = __builtin_amdgcn_mfma_i32_32x32x32_i8(a1, b2, acc3, 0, 0, 0);
        acc4 = __builtin_amdgcn_mfma_i32_32x32x32_i8(a2, b2, acc4, 0, 0, 0);
        acc1 = __builtin_amdgcn_mfma_i32_32x32x32_i8(a1, b0, acc1, 0, 0, 0);
        acc2 = __builtin_amdgcn_mfma_i32_32x32x32_i8(a1, b1, acc2, 0, 0, 0);
        acc3 = __builtin_amdgcn_mfma_i32_32x32x32_i8(a2, b1, acc3, 0, 0, 0);
        acc2 = __builtin_amdgcn_mfma_i32_32x32x32_i8(a2, b0, acc2, 0, 0, 0);
    }

    // All staging reads done -> red[] may alias the staging region.
    __syncthreads();
    unsigned* red = (unsigned*)lds;
#pragma unroll
    for (int r = 0; r < 16; ++r) {
        const unsigned v = (unsigned)acc0[r]
                         + ((unsigned)acc1[r] << 7)
                         + ((unsigned)acc2[r] << 14)
                         + ((unsigned)acc3[r] << 21)
                         + ((unsigned)acc4[r] << 28);
        const int idx = 32 * ((r & 3) + 8 * (r >> 2) + 4 * h) + n;
        red[(wv << 10) + idx] = v;
    }
    __syncthreads();

    const uint4* rb = (const uint4*)red;
    uint4 t0 = rb[l], t1 = rb[256 + l], t2 = rb[512 + l], t3 = rb[768 + l];
    const uint4 tot = make_uint4(t0.x + t1.x + t2.x + t3.x,
                                 t0.y + t1.y + t2.y + t3.y,
                                 t0.z + t1.z + t2.z + t3.z,
                                 t0.w + t1.w + t2.w + t3.w);
    *(uint4*)&part[(((size_t)blk * MAXU + id) << 10) + 4 * l] = tot;

    // ---- Threadfence reduction: last workgroup of this blk sums slices ----
    __threadfence();                              // release our partial
    if (l == 0) qSh = atomicAdd(&ctr[blk], 1u);   // device-scope
    __syncthreads();
    if ((int)qSh == un - 1) {
        __threadfence();                          // acquire all partials
        const unsigned* p = part + (((size_t)blk * MAXU) << 10) + 4 * l;
        uint4 s0 = make_uint4(0, 0, 0, 0), s1 = make_uint4(0, 0, 0, 0);
        int i = 0;
#pragma unroll 1
        for (; i + 2 <= un; i += 2) {             // 2 chains pipeline the loads
            const uint4 v0 = *(const uint4*)&p[(size_t)(i + 0) << 10];
            const uint4 v1 = *(const uint4*)&p[(size_t)(i + 1) << 10];
            s0.x += v0.x; s0.y += v0.y; s0.z += v0.z; s0.w += v0.w;
            s1.x += v1.x; s1.y += v1.y; s1.z += v1.z; s1.w += v1.w;
        }
        if (i < un) {
            const uint4 v0 = *(const uint4*)&p[(size_t)i << 10];
            s0.x += v0.x; s0.y += v0.y; s0.z += v0.z; s0.w += v0.w;
        }
        *(uint4*)&out[c0 + 4 * l] = make_uint4(s0.x + s1.x, s0.y + s1.y,
                                               s0.z + s1.z, s0.w + s1.w);
    }
}

// ---- Fallback (ws too small): verified R13 self-contained kernel ----
#define FAPL  1536
#define FBPL  608
#define FBOFF (3 * FAPL)
#define FABSZ (FBOFF + 12 * FBPL)
__global__ __launch_bounds__(TPB, 4) void conv_fb(
    const int* __restrict__ A, const int* __restrict__ B, unsigned* __restrict__ out)
{
    __shared__ __align__(16) char lds[FABSZ];
    __shared__ __align__(16) unsigned red[4096];

    int id = (int)blockIdx.x, blk = 0, Istart = 0, un = 0;
#pragma unroll 1
    for (; blk < NBC; ++blk) {
        blk_params(blk, 16, &Istart, &un);
        if (id < un) break;
        id -= un;
    }
    const int c0 = blk << 10, S0 = Istart + 512 * id;
    const int ATop = S0 + 1472, JB = c0 - S0 - 480;
    const int l = (int)threadIdx.x;

#pragma unroll
    for (int it = 0; it < 2; ++it) {
        const int w = l + (it << 8);
        if (w < 376) {
            const int x0 = ATop - 4 * w;
            const unsigned v0 = ldv(A, x0), v1 = ldv(A, x0 - 1);
            const unsigned v2 = ldv(A, x0 - 2), v3 = ldv(A, x0 - 3);
            const int wa = swzA(4 * w);
            *(unsigned*)&lds[0 * FAPL + wa] = pk4(v0 & 127, v1 & 127, v2 & 127, v3 & 127);
            *(unsigned*)&lds[1 * FAPL + wa] = pk4((v0 >> 7) & 127, (v1 >> 7) & 127,
                                                  (v2 >> 7) & 127, (v3 >> 7) & 127);
            *(unsigned*)&lds[2 * FAPL + wa] = pk4(v0 >> 14, v1 >> 14, v2 >> 14, v3 >> 14);
        }
    }
    if (l < 144) {
        const int j = JB + 4 * l;
        const unsigned u0 = ldv(B, j), u1 = ldv(B, j + 1), u2 = ldv(B, j + 2);
        const unsigned u3 = ldv(B, j + 3), u4 = ldv(B, j + 4), u5 = ldv(B, j + 5);
        const unsigned u6 = ldv(B, j + 6);
        const int wb = FBOFF + 4 * l;
#define FBPLANE(q, D0, D1, D2, D3, D4, D5, D6)                                  \
        *(unsigned*)&lds[wb + ((q)*4 + 0) * FBPL] = pk4(D0, D1, D2, D3);        \
        *(unsigned*)&lds[wb + ((q)*4 + 1) * FBPL] = pk4(D1, D2, D3, D4);        \
        *(unsigned*)&lds[wb + ((q)*4 + 2) * FBPL] = pk4(D2, D3, D4, D5);        \
        *(unsigned*)&lds[wb + ((q)*4 + 3) * FBPL] = pk4(D3, D4, D5, D6);
        FBPLANE(0, u0 & 127, u1 & 127, u2 & 127, u3 & 127, u4 & 127, u5 & 127, u6 & 127)
        FBPLANE(1, (u0 >> 7) & 127, (u1 >> 7) & 127, (u2 >> 7) & 127,
                   (u3 >> 7) & 127, (u4 >> 7) & 127, (u5 >> 7) & 127, (u6 >> 7) & 127)
        FBPLANE(2, u0 >> 14, u1 >> 14, u2 >> 14, u3 >> 14, u4 >> 14, u5 >> 14, u6 >> 14)
#undef FBPLANE
    }
    __syncthreads();

    const int wv = l >> 6, ll = l & 63, n = ll & 31, h = ll >> 5;
    const int aInv = 1472 + 16 * h - 32 * n;
    const int bInv = FBOFF + (n & 3) * FBPL + 4 * (120 + 4 * h + (n >> 2));
    i32x16 acc0 = z16(), acc1 = z16(), acc2 = z16(), acc3 = z16(), acc4 = z16();
#pragma unroll
    for (int j = 0; j < 4; ++j) {
        const int s = wv + 4 * j;
        const int aa = swzA(aInv - 32 * s);
        const i32x4 a0 = *(const i32x4*)&lds[0 * FAPL + aa];
        const i32x4 a1 = *(const i32x4*)&lds[1 * FAPL + aa];
        const i32x4 a2 = *(const i32x4*)&lds[2 * FAPL + aa];
        const int bb = bInv - 32 * s;
        i32x4 b0, b1, b2;
#pragma unroll
        for (int q = 0; q < 4; ++q) {
            b0[q] = *(const int*)&lds[bb + 0 * 4 * FBPL + 4 * q];
            b1[q] = *(const int*)&lds[bb + 1 * 4 * FBPL + 4 * q];
            b2[q] = *(const int*)&lds[bb + 2 * 4 * FBPL + 4 * q];
        }
        acc0 = __builtin_amdgcn_mfma_i32_32x32x32_i8(a0, b0, acc0, 0, 0, 0);
        acc1 = __builtin_amdgcn_mfma_i32_32x32x32_i8(a0, b1, acc1, 0, 0, 0);
        acc2 = __builtin_amdgcn_mfma_i32_32x32x32_i8(a0, b2, acc2, 0, 0, 0);
        acc3 = __builtin_amdgcn_mfma_i32_32x32x32_i8(a1, b2, acc3, 0, 0, 0);
        acc4 = __builtin_amdgcn_mfma_i32_32x32x32_i8(a2, b2, acc4, 0, 0, 0);
        acc1 = __builtin_amdgcn_mfma_i32_32x32x32_i8(a1, b0, acc1, 0, 0, 0);
        acc2 = __builtin_amdgcn_mfma_i32_32x32x32_i8(a1, b1, acc2, 0, 0, 0);
        acc3 = __builtin_amdgcn_mfma_i32_32x32x32_i8(a2, b1, acc3, 0, 0, 0);
        acc2 = __builtin_amdgcn_mfma_i32_32x32x32_i8(a2, b0, acc2, 0, 0, 0);
    }
    __syncthreads();
#pragma unroll
    for (int r = 0; r < 16; ++r) {
        const unsigned v = (unsigned)acc0[r] + ((unsigned)acc1[r] << 7)
                         + ((unsigned)acc2[r] << 14) + ((unsigned)acc3[r] << 21)
                         + ((unsigned)acc4[r] << 28);
        red[(wv << 10) + 32 * ((r & 3) + 8 * (r >> 2) + 4 * h) + n] = v;
    }
    __syncthreads();
    const uint4* rb = (const uint4*)red;
    uint4 t0 = rb[l], t1 = rb[256 + l], t2 = rb[512 + l], t3 = rb[768 + l];
    unsigned* o = out + c0 + 4 * l;
    atomicAdd(&o[0], t0.x + t1.x + t2.x + t3.x);
    atomicAdd(&o[1], t0.y + t1.y + t2.y + t3.y);
    atomicAdd(&o[2], t0.z + t1.z + t2.z + t3.z);
    atomicAdd(&o[3], t0.w + t1.w + t2.w + t3.w);
}

extern "C" void kernel_launch(void* const* d_in, const int* in_sizes, int n_in,
                              void* d_out, int out_size, void* d_ws, size_t ws_size,
                              hipStream_t stream)
{
    const int* A = (const int*)d_in[0];
    const int* B = (const int*)d_in[1];
    unsigned* out = (unsigned*)d_out;
    char* w8 = (char*)d_ws;

    const size_t need = (size_t)CTR_B + NBC * 4;   // ~9.5 MB
    if (ws_size >= need) {
        pack_kernel<<<dim3(36, 5), TPB, 0, stream>>>(A, B, w8);
        dim3 grid(MAXU, NBC);
        conv_mfma<<<grid, TPB, 0, stream>>>(w8 + GA_B, w8 + GB_B,
                                            (unsigned*)(w8 + PART_B),
                                            (unsigned*)(w8 + CTR_B), out);
    } else {
        hipMemsetAsync(d_out, 0, (size_t)out_size * sizeof(int), stream);
        int NU = 0;
        for (int b = 0; b < NBC; ++b) { int Is, un; blk_params(b, 16, &Is, &un); NU += un; }
        conv_fb<<<NU, TPB, 0, stream>>>(A, B, out);
    }
}

// Round 19
// 24.942 us; speedup vs baseline: 6.0092x; 6.0092x over previous
//
#include <hip/hip_runtime.h>

#define MM      32768
#define OUTN    65536
#define NBC     64                 // output blocks of 1024 bins
#define TPB     256
#define NSTW    32                 // i0-steps per unit
#define MAXU    34                 // max units per block (real max 33)
#define APL     2048               // A plane bytes in LDS (504 dw live)
#define AREG    (3 * APL)          // 6144
#define BPL     1096               // B (q,r) plane bytes in LDS (272 dw live)
#define LDSZ    (AREG + 12 * BPL)  // 19296; red[16KB] aliases lds[0..)
#define GASZ    9216               // gRA plane dwords
#define GBSZ    9216               // gB plane dwords
#define GG      2048               // gB leading guard bytes
#define AMAXTOP 34816              // global reversed-A origin limb (mult of 32)
#define GA_B    0
#define GB_B    (3 * GASZ * 4)     // 110592
#define PART_B  (GB_B + 12 * GBSZ * 4)  // 552960

typedef int i32x4  __attribute__((ext_vector_type(4)));
typedef int i32x16 __attribute__((ext_vector_type(16)));

__host__ __device__ inline void blk_params(int b, int nstw, int* Istart, int* units) {
    const int c0 = b << 10;
    int iLo = c0 - (MM - 1); if (iLo < 0) iLo = 0;
    int iHi = c0 + 1023;     if (iHi > MM - 1) iHi = MM - 1;
    const int Is = (iLo - 961) & ~31;
    const int Ie = (iHi + 31) & ~31;
    const int steps = ((Ie - Is) >> 5) + 1;
    *Istart = Is;
    *units  = (steps + nstw - 1) / nstw;
}

__device__ __forceinline__ int swzA(int a) {
    return a ^ ((a >> 2) & 0x30) ^ ((a >> 4) & 0x30);
}
__device__ __forceinline__ unsigned ldv(const int* __restrict__ p, int x) {
    return ((unsigned)x < (unsigned)MM) ? (unsigned)p[x] : 0u;
}
__device__ __forceinline__ unsigned pk4(unsigned b0, unsigned b1, unsigned b2, unsigned b3) {
    return b0 | (b1 << 8) | (b2 << 16) | (b3 << 24);
}
__device__ __forceinline__ i32x16 z16() {
    i32x16 v;
#pragma unroll
    for (int i = 0; i < 16; ++i) v[i] = 0;
    return v;
}

// grid (36, 5): y==0 -> reversed-A digit planes; y==r+1 -> B phase-r planes.
//  gRA_p byte u <-> digit_p(A[AMAXTOP - u]);  gB (q,r) byte g <-> digit_q(B[g - GG + r])
__global__ __launch_bounds__(TPB) void pack_kernel(
    const int* __restrict__ A, const int* __restrict__ B, char* __restrict__ w8)
{
    const int g4 = (int)blockIdx.x * TPB + (int)threadIdx.x;   // dword index < 9216
    if (blockIdx.y == 0) {
        unsigned* gRA = (unsigned*)(w8 + GA_B);
        const int x0 = AMAXTOP - 4 * g4;
        const unsigned v0 = ldv(A, x0),     v1 = ldv(A, x0 - 1);
        const unsigned v2 = ldv(A, x0 - 2), v3 = ldv(A, x0 - 3);
        gRA[0 * GASZ + g4] = pk4(v0 & 127, v1 & 127, v2 & 127, v3 & 127);
        gRA[1 * GASZ + g4] = pk4((v0 >> 7) & 127, (v1 >> 7) & 127,
                                 (v2 >> 7) & 127, (v3 >> 7) & 127);
        gRA[2 * GASZ + g4] = pk4(v0 >> 14, v1 >> 14, v2 >> 14, v3 >> 14);
    } else {
        const int r = (int)blockIdx.y - 1;                     // byte phase 0..3
        unsigned* gB = (unsigned*)(w8 + GB_B);
        const int L = 4 * g4 - GG + r;
        const unsigned u0 = ldv(B, L),     u1 = ldv(B, L + 1);
        const unsigned u2 = ldv(B, L + 2), u3 = ldv(B, L + 3);
        gB[(0 * 4 + r) * GBSZ + g4] = pk4(u0 & 127, u1 & 127, u2 & 127, u3 & 127);
        gB[(1 * 4 + r) * GBSZ + g4] = pk4((u0 >> 7) & 127, (u1 >> 7) & 127,
                                          (u2 >> 7) & 127, (u3 >> 7) & 127);
        gB[(2 * 4 + r) * GBSZ + g4] = pk4(u0 >> 14, u1 >> 14, u2 >> 14, u3 >> 14);
    }
}

// One workgroup = one unit: 1024 bins, 32 i0-steps (4 waves x 8 steps).
// Geometry = R13's verified kernel extended by +512 swept limbs:
//  A:  aa = swzA(1984 + 16h - 32n - 32s)
//  B:  bb = AREG + (n&3)*BPL + 4*(248 + 4h + (n>>2)) - 32s
// Staging is a pure dword copy from the pre-packed planes.
template <bool PARTIAL>
__global__ __launch_bounds__(TPB, 4) void conv_mfma(
    const char* __restrict__ gA, const char* __restrict__ gB,
    unsigned* __restrict__ part, unsigned* __restrict__ out)
{
    __shared__ __align__(16) char lds[LDSZ];

    const int blk = (int)blockIdx.y;
    const int id  = (int)blockIdx.x;
    int Istart, un;
    blk_params(blk, NSTW, &Istart, &un);
    if (id >= un) return;

    const int c0  = blk << 10;
    const int S0  = Istart + 1024 * id;
    const int OFA = (AMAXTOP - S0 - 1984) >> 2;   // gRA dword base
    const int OFB = (c0 - S0 + 1056) >> 2;        // gB dword base
    const int l   = (int)threadIdx.x;
    const unsigned* gA4 = (const unsigned*)gA;
    const unsigned* gB4 = (const unsigned*)gB;

    // ---- Stage A: 504 dwords x 3 planes, swizzled dest (pure copy) ----
#pragma unroll
    for (int it = 0; it < 2; ++it) {
        const int w = l + (it << 8);
        if (w < 504) {
            const int wa = swzA(4 * w);
            *(unsigned*)&lds[0 * APL + wa] = gA4[0 * GASZ + OFA + w];
            *(unsigned*)&lds[1 * APL + wa] = gA4[1 * GASZ + OFA + w];
            *(unsigned*)&lds[2 * APL + wa] = gA4[2 * GASZ + OFA + w];
        }
    }
    // ---- Stage B: 272 dwords x 12 (q,r) planes (pure copy) ----
#pragma unroll
    for (int pl = 0; pl < 12; ++pl) {
        *(unsigned*)&lds[AREG + pl * BPL + 4 * l] = gB4[pl * GBSZ + OFB + l];
    }
    if (l < 16) {
#pragma unroll
        for (int pl = 0; pl < 12; ++pl) {
            *(unsigned*)&lds[AREG + pl * BPL + 4 * (l + 256)] =
                gB4[pl * GBSZ + OFB + l + 256];
        }
    }
    __syncthreads();

    const int wv = l >> 6;
    const int ll = l & 63;
    const int n  = ll & 31, h = ll >> 5;
    const int A0 = 1984 + 16 * h - 32 * n;
    const int B0 = AREG + (n & 3) * BPL + 4 * (248 + 4 * h + (n >> 2));

    i32x16 acc0 = z16(), acc1 = z16(), acc2 = z16(), acc3 = z16(), acc4 = z16();

#pragma unroll
    for (int j = 0; j < 8; ++j) {
        const int s = wv + 4 * j;                 // this wave's 8 of 32 steps
        const int aa = swzA(A0 - 32 * s);
        const i32x4 a0 = *(const i32x4*)&lds[aa];
        const i32x4 a1 = *(const i32x4*)&lds[APL + aa];
        const i32x4 a2 = *(const i32x4*)&lds[2 * APL + aa];
        const int bb = B0 - 32 * s;
        i32x4 b0, b1, b2;
#pragma unroll
        for (int q = 0; q < 4; ++q) {
            b0[q] = *(const int*)&lds[bb + 4 * q];
            b1[q] = *(const int*)&lds[bb + 4 * BPL + 4 * q];
            b2[q] = *(const int*)&lds[bb + 8 * BPL + 4 * q];
        }
        acc0 = __builtin_amdgcn_mfma_i32_32x32x32_i8(a0, b0, acc0, 0, 0, 0);
        acc1 = __builtin_amdgcn_mfma_i32_32x32x32_i8(a0, b1, acc1, 0, 0, 0);
        acc2 = __builtin_amdgcn_mfma_i32_32x32x32_i8(a0, b2, acc2, 0, 0, 0);
        acc3 = __builtin_amdgcn_mfma_i32_32x32x32_i8(a1, b2, acc3, 0, 0, 0);
        acc4 = __builtin_amdgcn_mfma_i32_32x32x32_i8(a2, b2, acc4, 0, 0, 0);
        acc1 = __builtin_amdgcn_mfma_i32_32x32x32_i8(a1, b0, acc1, 0, 0, 0);
        acc2 = __builtin_amdgcn_mfma_i32_32x32x32_i8(a1, b1, acc2, 0, 0, 0);
        acc3 = __builtin_amdgcn_mfma_i32_32x32x32_i8(a2, b1, acc3, 0, 0, 0);
        acc2 = __builtin_amdgcn_mfma_i32_32x32x32_i8(a2, b0, acc2, 0, 0, 0);
    }

    // All staging reads done -> red[] may alias the staging region.
    __syncthreads();
    unsigned* red = (unsigned*)lds;
#pragma unroll
    for (int r = 0; r < 16; ++r) {
        const unsigned v = (unsigned)acc0[r]
                         + ((unsigned)acc1[r] << 7)
                         + ((unsigned)acc2[r] << 14)
                         + ((unsigned)acc3[r] << 21)
                         + ((unsigned)acc4[r] << 28);
        const int idx = 32 * ((r & 3) + 8 * (r >> 2) + 4 * h) + n;
        red[(wv << 10) + idx] = v;
    }
    __syncthreads();

    const uint4* rb = (const uint4*)red;
    uint4 t0 = rb[l], t1 = rb[256 + l], t2 = rb[512 + l], t3 = rb[768 + l];
    const uint4 tot = make_uint4(t0.x + t1.x + t2.x + t3.x,
                                 t0.y + t1.y + t2.y + t3.y,
                                 t0.z + t1.z + t2.z + t3.z,
                                 t0.w + t1.w + t2.w + t3.w);
    if (PARTIAL) {
        *(uint4*)&part[(((size_t)blk * MAXU + id) << 10) + 4 * l] = tot;
    } else {
        unsigned* o = out + c0 + 4 * l;
        atomicAdd(&o[0], tot.x); atomicAdd(&o[1], tot.y);
        atomicAdd(&o[2], tot.z); atomicAdd(&o[3], tot.w);
    }
}

// out[c] = sum over the owning block's valid unit slices (mod 2^32).
__global__ __launch_bounds__(TPB) void reduce_k(
    const unsigned* __restrict__ part, unsigned* __restrict__ out)
{
    const int c = (int)blockIdx.x * TPB + (int)threadIdx.x;
    const int blk = c >> 10;
    int Is, un;
    blk_params(blk, NSTW, &Is, &un);

    const unsigned* p = part + (((size_t)blk * MAXU) << 10) + (c & 1023);
    unsigned s0 = 0, s1 = 0, s2 = 0, s3 = 0;
    int i = 0;
#pragma unroll 1
    for (; i + 4 <= un; i += 4) {
        s0 += p[(size_t)(i + 0) << 10]; s1 += p[(size_t)(i + 1) << 10];
        s2 += p[(size_t)(i + 2) << 10]; s3 += p[(size_t)(i + 3) << 10];
    }
    for (; i < un; ++i) s0 += p[(size_t)i << 10];
    out[c] = s0 + s1 + s2 + s3;
}

// ---- Fallback (ws too small): verified R13 self-contained kernel ----
#define FAPL  1536
#define FBPL  608
#define FBOFF (3 * FAPL)
#define FABSZ (FBOFF + 12 * FBPL)
__global__ __launch_bounds__(TPB, 4) void conv_fb(
    const int* __restrict__ A, const int* __restrict__ B, unsigned* __restrict__ out)
{
    __shared__ __align__(16) char lds[FABSZ];
    __shared__ __align__(16) unsigned red[4096];

    int id = (int)blockIdx.x, blk = 0, Istart = 0, un = 0;
#pragma unroll 1
    for (; blk < NBC; ++blk) {
        blk_params(blk, 16, &Istart, &un);
        if (id < un) break;
        id -= un;
    }
    const int c0 = blk << 10, S0 = Istart + 512 * id;
    const int ATop = S0 + 1472, JB = c0 - S0 - 480;
    const int l = (int)threadIdx.x;

#pragma unroll
    for (int it = 0; it < 2; ++it) {
        const int w = l + (it << 8);
        if (w < 376) {
            const int x0 = ATop - 4 * w;
            const unsigned v0 = ldv(A, x0), v1 = ldv(A, x0 - 1);
            const unsigned v2 = ldv(A, x0 - 2), v3 = ldv(A, x0 - 3);
            const int wa = swzA(4 * w);
            *(unsigned*)&lds[0 * FAPL + wa] = pk4(v0 & 127, v1 & 127, v2 & 127, v3 & 127);
            *(unsigned*)&lds[1 * FAPL + wa] = pk4((v0 >> 7) & 127, (v1 >> 7) & 127,
                                                  (v2 >> 7) & 127, (v3 >> 7) & 127);
            *(unsigned*)&lds[2 * FAPL + wa] = pk4(v0 >> 14, v1 >> 14, v2 >> 14, v3 >> 14);
        }
    }
    if (l < 144) {
        const int j = JB + 4 * l;
        const unsigned u0 = ldv(B, j), u1 = ldv(B, j + 1), u2 = ldv(B, j + 2);
        const unsigned u3 = ldv(B, j + 3), u4 = ldv(B, j + 4), u5 = ldv(B, j + 5);
        const unsigned u6 = ldv(B, j + 6);
        const int wb = FBOFF + 4 * l;
#define FBPLANE(q, D0, D1, D2, D3, D4, D5, D6)                                  \
        *(unsigned*)&lds[wb + ((q)*4 + 0) * FBPL] = pk4(D0, D1, D2, D3);        \
        *(unsigned*)&lds[wb + ((q)*4 + 1) * FBPL] = pk4(D1, D2, D3, D4);        \
        *(unsigned*)&lds[wb + ((q)*4 + 2) * FBPL] = pk4(D2, D3, D4, D5);        \
        *(unsigned*)&lds[wb + ((q)*4 + 3) * FBPL] = pk4(D3, D4, D5, D6);
        FBPLANE(0, u0 & 127, u1 & 127, u2 & 127, u3 & 127, u4 & 127, u5 & 127, u6 & 127)
        FBPLANE(1, (u0 >> 7) & 127, (u1 >> 7) & 127, (u2 >> 7) & 127,
                   (u3 >> 7) & 127, (u4 >> 7) & 127, (u5 >> 7) & 127, (u6 >> 7) & 127)
        FBPLANE(2, u0 >> 14, u1 >> 14, u2 >> 14, u3 >> 14, u4 >> 14, u5 >> 14, u6 >> 14)
#undef FBPLANE
    }
    __syncthreads();

    const int wv = l >> 6, ll = l & 63, n = ll & 31, h = ll >> 5;
    const int aInv = 1472 + 16 * h - 32 * n;
    const int bInv = FBOFF + (n & 3) * FBPL + 4 * (120 + 4 * h + (n >> 2));
    i32x16 acc0 = z16(), acc1 = z16(), acc2 = z16(), acc3 = z16(), acc4 = z16();
#pragma unroll
    for (int j = 0; j < 4; ++j) {
        const int s = wv + 4 * j;
        const int aa = swzA(aInv - 32 * s);
        const i32x4 a0 = *(const i32x4*)&lds[0 * FAPL + aa];
        const i32x4 a1 = *(const i32x4*)&lds[1 * FAPL + aa];
        const i32x4 a2 = *(const i32x4*)&lds[2 * FAPL + aa];
        const int bb = bInv - 32 * s;
        i32x4 b0, b1, b2;
#pragma unroll
        for (int q = 0; q < 4; ++q) {
            b0[q] = *(const int*)&lds[bb + 0 * 4 * FBPL + 4 * q];
            b1[q] = *(const int*)&lds[bb + 1 * 4 * FBPL + 4 * q];
            b2[q] = *(const int*)&lds[bb + 2 * 4 * FBPL + 4 * q];
        }
        acc0 = __builtin_amdgcn_mfma_i32_32x32x32_i8(a0, b0, acc0, 0, 0, 0);
        acc1 = __builtin_amdgcn_mfma_i32_32x32x32_i8(a0, b1, acc1, 0, 0, 0);
        acc2 = __builtin_amdgcn_mfma_i32_32x32x32_i8(a0, b2, acc2, 0, 0, 0);
        acc3 = __builtin_amdgcn_mfma_i32_32x32x32_i8(a1, b2, acc3, 0, 0, 0);
        acc4 = __builtin_amdgcn_mfma_i32_32x32x32_i8(a2, b2, acc4, 0, 0, 0);
        acc1 = __builtin_amdgcn_mfma_i32_32x32x32_i8(a1, b0, acc1, 0, 0, 0);
        acc2 = __builtin_amdgcn_mfma_i32_32x32x32_i8(a1, b1, acc2, 0, 0, 0);
        acc3 = __builtin_amdgcn_mfma_i32_32x32x32_i8(a2, b1, acc3, 0, 0, 0);
        acc2 = __builtin_amdgcn_mfma_i32_32x32x32_i8(a2, b0, acc2, 0, 0, 0);
    }
    __syncthreads();
#pragma unroll
    for (int r = 0; r < 16; ++r) {
        const unsigned v = (unsigned)acc0[r] + ((unsigned)acc1[r] << 7)
                         + ((unsigned)acc2[r] << 14) + ((unsigned)acc3[r] << 21)
                         + ((unsigned)acc4[r] << 28);
        red[(wv << 10) + 32 * ((r & 3) + 8 * (r >> 2) + 4 * h) + n] = v;
    }
    __syncthreads();
    const uint4* rb = (const uint4*)red;
    uint4 t0 = rb[l], t1 = rb[256 + l], t2 = rb[512 + l], t3 = rb[768 + l];
    unsigned* o = out + c0 + 4 * l;
    atomicAdd(&o[0], t0.x + t1.x + t2.x + t3.x);
    atomicAdd(&o[1], t0.y + t1.y + t2.y + t3.y);
    atomicAdd(&o[2], t0.z + t1.z + t2.z + t3.z);
    atomicAdd(&o[3], t0.w + t1.w + t2.w + t3.w);
}

extern "C" void kernel_launch(void* const* d_in, const int* in_sizes, int n_in,
                              void* d_out, int out_size, void* d_ws, size_t ws_size,
                              hipStream_t stream)
{
    const int* A = (const int*)d_in[0];
    const int* B = (const int*)d_in[1];
    unsigned* out = (unsigned*)d_out;
    char* w8 = (char*)d_ws;

    const size_t need = (size_t)PART_B + (size_t)NBC * MAXU * 1024 * 4;  // ~9.5 MB
    if (ws_size >= need) {
        pack_kernel<<<dim3(36, 5), TPB, 0, stream>>>(A, B, w8);
        dim3 grid(MAXU, NBC);
        conv_mfma<true><<<grid, TPB, 0, stream>>>(w8 + GA_B, w8 + GB_B,
                                                  (unsigned*)(w8 + PART_B), out);
        reduce_k<<<OUTN / TPB, TPB, 0, stream>>>((unsigned*)(w8 + PART_B), out);
    } else {
        hipMemsetAsync(d_out, 0, (size_t)out_size * sizeof(int), stream);
        int NU = 0;
        for (int b = 0; b < NBC; ++b) { int Is, un; blk_params(b, 16, &Is, &un); NU += un; }
        conv_fb<<<NU, TPB, 0, stream>>>(A, B, out);
    }
}